// Round 2
// baseline (137.739 us; speedup 1.0000x reference)
//
#include <hip/hip_runtime.h>

// COO SpMM: out[r,:] = sum_e vals[e] * seq[cols[e],:], rows sorted.
// N=50000, E=1.25M, D=64, fp32.
//
// R1 analysis: FETCH_SIZE 117.5 MB == per-XCD compulsory floor (8 XCD x
// 12.8 MB seq + 15 MB metadata) -> traffic is optimal; kernel is
// LATENCY-bound (VALUBusy 21%, 2.3 TB/s of ~6.3 achievable).
// R2: explicit software pipeline — double-buffered batches of 16 gather
// loads so each wave keeps 16-32 vmem ops in flight continuously.

#define D_FEAT 64
#define EPW 128              // edges per wave
#define WAVES_PER_BLOCK 4    // 256-thread blocks

__global__ __launch_bounds__(256) void spmm_coo_kernel(
    const float* __restrict__ seq,   // [N, 64]
    const float* __restrict__ vals,  // [E]
    const int*   __restrict__ rows,  // [E] sorted
    const int*   __restrict__ cols,  // [E]
    float*       __restrict__ out,   // [N, 64], pre-zeroed
    int n_edges)
{
    const int lane = threadIdx.x & 63;
    const int wave = blockIdx.x * WAVES_PER_BLOCK + (threadIdx.x >> 6);

    const long long s_ll = (long long)wave * EPW;
    if (s_ll >= n_edges) return;
    const int s   = (int)s_ll;
    const int rem = n_edges - s;

    int   cur_row = rows[s];   // wave-uniform broadcast load
    float acc     = 0.f;

    if (rem >= EPW) {
        // ---- fast path: exactly 128 edges ----
        // metadata: 2 edges per lane, coalesced, nontemporal (streamed once;
        // don't evict seq from L2)
        const int e0 = s + lane, e1 = s + 64 + lane;
        const int   r0 = __builtin_nontemporal_load(rows + e0);
        const int   c0 = __builtin_nontemporal_load(cols + e0);
        const float v0 = __builtin_nontemporal_load(vals + e0);
        const int   r1 = __builtin_nontemporal_load(rows + e1);
        const int   c1 = __builtin_nontemporal_load(cols + e1);
        const float v1 = __builtin_nontemporal_load(vals + e1);

        float x[2][16];

        // prologue: issue batch 0 (16 gathers)
#pragma unroll
        for (int u = 0; u < 16; ++u) {
            const int cj = __shfl(c0, u);
            x[0][u] = seq[cj * D_FEAT + lane];
        }

#pragma unroll
        for (int b = 0; b < 8; ++b) {
            const int cur = b & 1;
            const int nxt = cur ^ 1;
            // issue batch b+1 BEFORE consuming batch b -> loads stay in flight
            if (b + 1 < 8) {
#pragma unroll
                for (int u = 0; u < 16; ++u) {
                    const int j  = (b + 1) * 16 + u;
                    const int cj = (j < 64) ? __shfl(c0, j) : __shfl(c1, j - 64);
                    x[nxt][u] = seq[cj * D_FEAT + lane];
                }
            }
            // consume batch b
#pragma unroll
            for (int u = 0; u < 16; ++u) {
                const int   j  = b * 16 + u;
                const int   rj = (j < 64) ? __shfl(r0, j) : __shfl(r1, j - 64);
                const float vj = (j < 64) ? __shfl(v0, j) : __shfl(v1, j - 64);
                if (rj != cur_row) {          // wave-uniform branch
                    atomicAdd(&out[cur_row * D_FEAT + lane], acc);
                    cur_row = rj;
                    acc = 0.f;
                }
                acc = fmaf(vj, x[cur][u], acc);
            }
        }
    } else {
        // ---- tail: last wave only (rem < 128 edges) ----
        for (int j = 0; j < rem; ++j) {
            const int   e  = s + j;
            const int   rj = rows[e];   // same addr all lanes -> broadcast
            const int   cj = cols[e];
            const float vj = vals[e];
            if (rj != cur_row) {
                atomicAdd(&out[cur_row * D_FEAT + lane], acc);
                cur_row = rj;
                acc = 0.f;
            }
            acc = fmaf(vj, seq[cj * D_FEAT + lane], acc);
        }
    }

    atomicAdd(&out[cur_row * D_FEAT + lane], acc);
}

extern "C" void kernel_launch(void* const* d_in, const int* in_sizes, int n_in,
                              void* d_out, int out_size, void* d_ws, size_t ws_size,
                              hipStream_t stream) {
    const float* seq  = (const float*)d_in[0];
    const float* vals = (const float*)d_in[1];
    const int*   rows = (const int*)d_in[2];
    const int*   cols = (const int*)d_in[3];
    float*       out  = (float*)d_out;

    const int n_edges = in_sizes[1];  // E

    // out is poisoned 0xAA before every timed call -> zero it every call
    hipMemsetAsync(d_out, 0, (size_t)out_size * sizeof(float), stream);

    const int waves  = (n_edges + EPW - 1) / EPW;
    const int blocks = (waves + WAVES_PER_BLOCK - 1) / WAVES_PER_BLOCK;
    spmm_coo_kernel<<<blocks, 256, 0, stream>>>(seq, vals, rows, cols, out, n_edges);
}